// Round 1
// baseline (162.210 us; speedup 1.0000x reference)
//
#include <hip/hip_runtime.h>

// LocalWindowAttention: B=1, H=8, S=4096, D=128, WINDOW=256, fp32 in/out.
// Tiled non-online flash: 64 q-rows/block, 5 K-tiles of 64 keys, scores
// retained in registers across tiles -> exact single-pass softmax.

constexpr int QB  = 64;     // query rows per block
constexpr int KB  = 64;     // keys per tile
constexpr int DH  = 128;    // head dim
constexpr int WIN = 256;    // window size
constexpr int NT  = WIN / KB + 1;   // 5 tiles cover [q0-256, q0+63]
constexpr int SKV = 132;    // LDS row stride (floats) for Q/K/V tiles (pad -> <=2-way banks)
constexpr int SP  = 68;     // LDS row stride for P tile
constexpr float SCALE = 0.08838834764831844f;  // 1/sqrt(128)

__global__ __launch_bounds__(256, 2)
void lwa_fp32(const float* __restrict__ qg, const float* __restrict__ kg,
              const float* __restrict__ vg, float* __restrict__ og, int S) {
  __shared__ float q_s[QB * SKV];   // Q (pass 1), reused as P with stride SP (pass 2)
  __shared__ float kv_s[KB * SKV];  // K tile (pass 1), V tile (pass 2)

  const int h   = blockIdx.y;
  const int q0  = blockIdx.x * QB;
  const int tid = threadIdx.x;
  const int tr  = tid >> 4;   // 0..15 : row group (4 rows each)
  const int tc  = tid & 15;   // 0..15 : col group

  const float* qb = qg + ((size_t)h * S + q0) * DH;
  const float* kb = kg + (size_t)h * S * DH;
  const float* vb = vg + (size_t)h * S * DH;

  // ---- stage Q tile, pre-scaled (coalesced float4, 8 per thread) ----
#pragma unroll
  for (int i = 0; i < 8; ++i) {
    int idx = tid + 256 * i;          // float4 index in 64x128 tile
    int r = idx >> 5, d = (idx & 31) << 2;
    float4 t4 = *(const float4*)(qb + r * DH + d);
    t4.x *= SCALE; t4.y *= SCALE; t4.z *= SCALE; t4.w *= SCALE;
    *(float4*)(&q_s[r * SKV + d]) = t4;
  }

  float acc[NT][4][4];                // scores: rows 4*tr+i, cols tc+16*j
#pragma unroll
  for (int t = 0; t < NT; ++t)
#pragma unroll
    for (int i = 0; i < 4; ++i)
#pragma unroll
      for (int j = 0; j < 4; ++j) acc[t][i][j] = 0.f;

  // ---- pass 1: S = Q K^T over 5 K tiles ----
#pragma unroll
  for (int t = 0; t < NT; ++t) {
    const int kt0 = q0 - WIN + t * KB;       // tile fully OOB or fully in-range
    if (kt0 < 0) continue;                   // uniform per block
    __syncthreads();                         // prior kv_s reads done
    const float* kt = kb + (size_t)kt0 * DH;
#pragma unroll
    for (int i = 0; i < 8; ++i) {
      int idx = tid + 256 * i;
      int r = idx >> 5, d = (idx & 31) << 2;
      *(float4*)(&kv_s[r * SKV + d]) = *(const float4*)(kt + r * DH + d);
    }
    __syncthreads();
#pragma unroll 2
    for (int d4 = 0; d4 < DH; d4 += 4) {
      float4 qv[4], kv[4];
#pragma unroll
      for (int i = 0; i < 4; ++i)
        qv[i] = *(const float4*)(&q_s[(4 * tr + i) * SKV + d4]);
#pragma unroll
      for (int j = 0; j < 4; ++j)
        kv[j] = *(const float4*)(&kv_s[(tc + 16 * j) * SKV + d4]);
#pragma unroll
      for (int i = 0; i < 4; ++i)
#pragma unroll
        for (int j = 0; j < 4; ++j)
          acc[t][i][j] += qv[i].x * kv[j].x + qv[i].y * kv[j].y +
                          qv[i].z * kv[j].z + qv[i].w * kv[j].w;
    }
  }

  // ---- softmax over the window (exact, scores all in regs) ----
  float rl[4];
#pragma unroll
  for (int i = 0; i < 4; ++i) {
    const int qi = q0 + 4 * tr + i;
    float m = -3.0e38f;
#pragma unroll
    for (int t = 0; t < NT; ++t)
#pragma unroll
      for (int j = 0; j < 4; ++j) {
        const int ki = q0 - WIN + t * KB + tc + 16 * j;
        const bool ok = (ki >= 0) && (ki <= qi) && (ki > qi - WIN);
        float s = ok ? acc[t][i][j] : -3.0e38f;
        acc[t][i][j] = s;
        m = fmaxf(m, s);
      }
#pragma unroll
    for (int w = 1; w < 16; w <<= 1) m = fmaxf(m, __shfl_xor(m, w, 16));
    float l = 0.f;
#pragma unroll
    for (int t = 0; t < NT; ++t)
#pragma unroll
      for (int j = 0; j < 4; ++j) {
        float p = __expf(acc[t][i][j] - m);  // masked: exp(-inf) = 0
        acc[t][i][j] = p;
        l += p;
      }
#pragma unroll
    for (int w = 1; w < 16; w <<= 1) l += __shfl_xor(l, w, 16);
    rl[i] = 1.f / l;                         // fold 1/l into epilogue
  }

  // ---- pass 2: O = P V over 5 V tiles ----
  float o[4][8];
#pragma unroll
  for (int i = 0; i < 4; ++i)
#pragma unroll
    for (int c = 0; c < 8; ++c) o[i][c] = 0.f;

#pragma unroll
  for (int t = 0; t < NT; ++t) {
    const int kt0 = q0 - WIN + t * KB;
    if (kt0 < 0) continue;
    __syncthreads();                         // prior P/V reads + pass-1 q_s reads done
#pragma unroll
    for (int i = 0; i < 4; ++i)
#pragma unroll
      for (int j = 0; j < 4; ++j)
        q_s[(4 * tr + i) * SP + tc + 16 * j] = acc[t][i][j];
    const float* vt = vb + (size_t)kt0 * DH;
#pragma unroll
    for (int i = 0; i < 8; ++i) {
      int idx = tid + 256 * i;
      int r = idx >> 5, d = (idx & 31) << 2;
      *(float4*)(&kv_s[r * SKV + d]) = *(const float4*)(vt + r * DH + d);
    }
    __syncthreads();
#pragma unroll 4
    for (int kk = 0; kk < KB; ++kk) {
      float4 v0 = *(const float4*)(&kv_s[kk * SKV + 4 * tc]);
      float4 v1 = *(const float4*)(&kv_s[kk * SKV + 4 * tc + 64]);
#pragma unroll
      for (int i = 0; i < 4; ++i) {
        float p = q_s[(4 * tr + i) * SP + kk];
        o[i][0] += p * v0.x; o[i][1] += p * v0.y;
        o[i][2] += p * v0.z; o[i][3] += p * v0.w;
        o[i][4] += p * v1.x; o[i][5] += p * v1.y;
        o[i][6] += p * v1.z; o[i][7] += p * v1.w;
      }
    }
  }

  // ---- epilogue: scale by 1/l, coalesced float4 stores ----
  float* ob = og + ((size_t)h * S + q0) * DH;
#pragma unroll
  for (int i = 0; i < 4; ++i) {
    float4 r0 = make_float4(o[i][0] * rl[i], o[i][1] * rl[i],
                            o[i][2] * rl[i], o[i][3] * rl[i]);
    float4 r1 = make_float4(o[i][4] * rl[i], o[i][5] * rl[i],
                            o[i][6] * rl[i], o[i][7] * rl[i]);
    *(float4*)(ob + (4 * tr + i) * DH + 4 * tc) = r0;
    *(float4*)(ob + (4 * tr + i) * DH + 4 * tc + 64) = r1;
  }
}

extern "C" void kernel_launch(void* const* d_in, const int* in_sizes, int n_in,
                              void* d_out, int out_size, void* d_ws, size_t ws_size,
                              hipStream_t stream) {
  const float* q = (const float*)d_in[0];
  const float* k = (const float*)d_in[1];
  const float* v = (const float*)d_in[2];
  float* out = (float*)d_out;
  const int H = 8, D = 128;
  const int S = in_sizes[0] / (H * D);   // 4096
  dim3 grid(S / QB, H);                  // 64 x 8 = 512 blocks = 2/CU
  lwa_fp32<<<grid, 256, 0, stream>>>(q, k, v, out, S);
}

// Round 3
// 112.147 us; speedup vs baseline: 1.4464x; 1.4464x over previous
//
#include <hip/hip_runtime.h>

// LocalWindowAttention B=1 H=8 S=4096 D=128 WIN=256, fp32 in/out.
// MFMA version: QK^T = 3-term bf16 hi/lo split; PV = plain bf16.
// 1 block = 64 q-rows x 1 head; 4 waves x 16 rows; scores in regs (exact softmax).

typedef short  bf16x8 __attribute__((ext_vector_type(8)));   // 8 bf16 bits
typedef __bf16 bf16v8 __attribute__((ext_vector_type(8)));   // builtin operand type
typedef float  f32x4  __attribute__((ext_vector_type(4)));

constexpr int QB = 64, DH = 128, WIN = 256, KT = 64;
constexpr int NTILE = 5, NSUB = 20;           // 5 x 64-key tiles, 20 x 16-key subtiles
constexpr float SCALE = 0.08838834764831844f; // 1/sqrt(128)

// LDS map (bytes):
//  region0: Khi [0,16384), Klo [16384,32768)       (pass 1)
//           P   [0,41984) = 64 rows x 328 bf16     (pass 2, aliases K)
//  Vt: [43008, 43008+16384) = 128 x 64 bf16, xor-swizzled
constexpr int KLO_OFF = 16384;
constexpr int PSTR    = 328;     // bf16 per P row (pad 8 -> 2-way banks)
constexpr int VT_OFF  = 43008;
constexpr int SMEM_BYTES = VT_OFF + 16384;

__device__ __forceinline__ short bf16_of(float x) {   // RNE truncation
  union { float f; unsigned u; } a; a.f = x;
  unsigned r = a.u + 0x7fffu + ((a.u >> 16) & 1u);
  return (short)(r >> 16);
}
__device__ __forceinline__ float f_of(short s) {
  union { float f; unsigned u; } a; a.u = ((unsigned)(unsigned short)s) << 16;
  return a.f;
}
__device__ __forceinline__ bf16v8 as_bf(bf16x8 s) {
  union { bf16x8 s; bf16v8 b; } u; u.s = s; return u.b;
}
#define MFMA(A, B, C) __builtin_amdgcn_mfma_f32_16x16x32_bf16(as_bf(A), as_bf(B), (C), 0, 0, 0)

__global__ __launch_bounds__(256, 2)
void lwa_mfma(const float* __restrict__ qg, const float* __restrict__ kg,
              const float* __restrict__ vg, float* __restrict__ og, int S) {
  __shared__ __align__(16) char smem[SMEM_BYTES];

  const int h   = blockIdx.y;
  const int q0  = blockIdx.x * QB;
  const int tid = threadIdx.x;
  const int wv  = tid >> 6;        // wave 0..3 -> q rows [16wv, 16wv+16)
  const int lane = tid & 63;
  const int lg  = lane >> 4;       // 0..3 (k-group)
  const int lm  = lane & 15;       // row/col within 16

  const float* qb = qg + ((size_t)h * S) * DH;
  const float* kb = kg + ((size_t)h * S) * DH;
  const float* vb = vg + ((size_t)h * S) * DH;

  // ---- Q fragments: global -> reg, scaled, hi/lo split. A-frag: row=lm, k=8*lg+j ----
  bf16x8 qhi[4], qlo[4];
  {
    const float* qrow = qb + ((size_t)(q0 + 16 * wv + lm)) * DH;
#pragma unroll
    for (int kc = 0; kc < 4; ++kc) {
      const int d0 = 32 * kc + 8 * lg;
      float4 a = *(const float4*)(qrow + d0);
      float4 b = *(const float4*)(qrow + d0 + 4);
      float x[8] = {a.x, a.y, a.z, a.w, b.x, b.y, b.z, b.w};
      bf16x8 hi, lo;
#pragma unroll
      for (int j = 0; j < 8; ++j) {
        float xs = x[j] * SCALE;
        short hs = bf16_of(xs);
        hi[j] = hs;
        lo[j] = bf16_of(xs - f_of(hs));
      }
      qhi[kc] = hi; qlo[kc] = lo;
    }
  }

  f32x4 acc[NSUB];
#pragma unroll
  for (int t = 0; t < NSUB; ++t) acc[t] = (f32x4){0.f, 0.f, 0.f, 0.f};

  const int srow = tid >> 4;        // staging: row within 16-row group
  const int sd0  = 8 * (tid & 15);  // staging: first d (8 consecutive)

  // ---- pass 1: S = Q K^T, 5 staged K tiles ----
  for (int t = 0; t < NTILE; ++t) {
    const int kt0 = q0 - WIN + t * KT;
    if (kt0 < 0) continue;                    // block-uniform
    __syncthreads();                          // prior tile's reads done
#pragma unroll
    for (int i = 0; i < 4; ++i) {             // stage K tile hi/lo, swizzled
      const int row = srow + 16 * i;
      const float* kr = kb + ((size_t)(kt0 + row)) * DH + sd0;
      float4 a = *(const float4*)(kr);
      float4 b = *(const float4*)(kr + 4);
      float x[8] = {a.x, a.y, a.z, a.w, b.x, b.y, b.z, b.w};
      bf16x8 hi, lo;
#pragma unroll
      for (int j = 0; j < 8; ++j) {
        short hs = bf16_of(x[j]);
        hi[j] = hs;
        lo[j] = bf16_of(x[j] - f_of(hs));
      }
      const int byte = row * 256 + ((sd0 * 2) ^ ((row & 15) << 4));
      *(bf16x8*)(smem + byte) = hi;
      *(bf16x8*)(smem + KLO_OFF + byte) = lo;
    }
    __syncthreads();
#pragma unroll
    for (int n = 0; n < 4; ++n) {             // 16-key subtiles
      f32x4 c = acc[4 * t + n];
#pragma unroll
      for (int kc = 0; kc < 4; ++kc) {
        const int key = 16 * n + lm;
        const int byte = key * 256 + (((64 * kc) + 16 * lg) ^ (lm << 4));
        bf16x8 kh = *(const bf16x8*)(smem + byte);
        bf16x8 kl = *(const bf16x8*)(smem + KLO_OFF + byte);
        c = MFMA(qhi[kc], kh, c);
        c = MFMA(qlo[kc], kh, c);
        c = MFMA(qhi[kc], kl, c);
      }
      acc[4 * t + n] = c;
    }
  }
  __syncthreads();   // all K reads done before P overwrites region0

  // ---- softmax: exact, in registers. Row r lives in reg r, cols across 16 lanes ----
  float rl[4];
#pragma unroll
  for (int r = 0; r < 4; ++r) {
    const int qi = q0 + 16 * wv + 4 * lg + r;
    float m = -3.0e38f;
#pragma unroll
    for (int ts = 0; ts < NSUB; ++ts) {
      const int ki = q0 - WIN + 16 * ts + lm;
      const bool ok = (ki >= 0) && (ki <= qi) && (ki > qi - WIN);
      float s = ok ? acc[ts][r] : -3.0e38f;
      acc[ts][r] = s;
      m = fmaxf(m, s);
    }
#pragma unroll
    for (int msk = 1; msk < 16; msk <<= 1) m = fmaxf(m, __shfl_xor(m, msk));
    float l = 0.f;
#pragma unroll
    for (int ts = 0; ts < NSUB; ++ts) {
      float p = __expf(acc[ts][r] - m);
      acc[ts][r] = p;
      l += p;
    }
#pragma unroll
    for (int msk = 1; msk < 16; msk <<= 1) l += __shfl_xor(l, msk);
    rl[r] = 1.f / l;
  }

  // ---- write P (bf16) to LDS: row = q-row, col = key-rel, stride 328 ----
#pragma unroll
  for (int ts = 0; ts < NSUB; ++ts)
#pragma unroll
    for (int r = 0; r < 4; ++r) {
      const int row = 16 * wv + 4 * lg + r;
      const int col = 16 * ts + lm;
      *(short*)(smem + row * (PSTR * 2) + col * 2) = bf16_of(acc[ts][r]);
    }

  // ---- pass 2: O = P V, 5 staged (transposed) V tiles ----
  f32x4 o[8];
#pragma unroll
  for (int n = 0; n < 8; ++n) o[n] = (f32x4){0.f, 0.f, 0.f, 0.f};

  for (int t = 0; t < NTILE; ++t) {
    const int kt0 = q0 - WIN + t * KT;
    if (kt0 < 0) continue;
    __syncthreads();                          // P ready / prior V reads done
#pragma unroll
    for (int i = 0; i < 4; ++i) {             // stage V^T, swizzled, bf16
      const int key = srow + 16 * i;
      const float* vr = vb + ((size_t)(kt0 + key)) * DH + sd0;
      float4 a = *(const float4*)(vr);
      float4 b = *(const float4*)(vr + 4);
      float x[8] = {a.x, a.y, a.z, a.w, b.x, b.y, b.z, b.w};
#pragma unroll
      for (int j = 0; j < 8; ++j) {
        const int d = sd0 + j;
        const int swz = ((d & 7) ^ ((d >> 3) & 7)) << 4;
        const int byte = d * 128 + ((key * 2) ^ swz);
        *(short*)(smem + VT_OFF + byte) = bf16_of(x[j]);
      }
    }
    __syncthreads();
#pragma unroll
    for (int kc = 0; kc < 2; ++kc) {          // 32-key chunks
      const int colb = (16 * wv + lm) * (PSTR * 2) + 128 * t + 64 * kc + 16 * lg;
      bf16x8 pf = *(const bf16x8*)(smem + colb);
#pragma unroll
      for (int n = 0; n < 8; ++n) {
        const int d = 16 * n + lm;
        const int swz = ((d & 7) ^ ((d >> 3) & 7)) << 4;
        const int byte = d * 128 + ((64 * kc + 16 * lg) ^ swz);
        bf16x8 vf = *(const bf16x8*)(smem + VT_OFF + byte);
        o[n] = MFMA(pf, vf, o[n]);
      }
    }
  }

  // ---- epilogue: scale by 1/l, store fp32 ----
  float* orow = og + ((size_t)(h * S + q0 + 16 * wv)) * DH;
#pragma unroll
  for (int n = 0; n < 8; ++n)
#pragma unroll
    for (int r = 0; r < 4; ++r)
      orow[(4 * lg + r) * DH + 16 * n + lm] = o[n][r] * rl[r];
}

extern "C" void kernel_launch(void* const* d_in, const int* in_sizes, int n_in,
                              void* d_out, int out_size, void* d_ws, size_t ws_size,
                              hipStream_t stream) {
  const float* q = (const float*)d_in[0];
  const float* k = (const float*)d_in[1];
  const float* v = (const float*)d_in[2];
  float* out = (float*)d_out;
  const int H = 8, D = 128;
  const int S = in_sizes[0] / (H * D);   // 4096
  dim3 grid(S / QB, H);                  // 64 x 8 = 512 blocks
  lwa_mfma<<<grid, 256, 0, stream>>>(q, k, v, out, S);
}